// Round 11
// baseline (175.045 us; speedup 1.0000x reference)
//
#include <hip/hip_runtime.h>
#include <hip/hip_bf16.h>

// SelfAttention: O = softmax(mask((X_q WQ)(X_k WK)^T/8)) (X_v WV), causal +
// key-padding (V_len) + query (Q_len) masks. B=8 S=1024 D=1024 H=16 Dh=64.
//
// All intermediates FP16. Pipeline:
//   prep    : (merged) X fp32->fp16 streams + Wt[3][n][k] transpose
//   proj    : ONE dispatch, 768 blocks; 128x256 tile, 4 waves x (128x64) --
//             8x4 frags, 32 MFMA/wave/step; 29 FLOP per LDS byte (was 22:
//             LDS-BW-bound at 28% MfmaUtil). global_load_lds w16 into THREE
//             rotating buffers, counted vmcnt(6) (loads live across barriers),
//             XOR-granule swizzle src+read (conflict-free ds_read_b128).
//   attn_fwd: flash attention, shift-free softmax, vlen tile skipping, fused
//             q-tile pairs {15-z, z} per block (K/V tiles loaded once).

#define B_  8
#define S_  1024
#define D_  1024
#define H_  16
#define DH_ 64

using f16x8  = __attribute__((ext_vector_type(8))) _Float16;
using h16x2  = __attribute__((ext_vector_type(2))) __fp16;  // cvt_pkrtz result
using s16x8  = __attribute__((ext_vector_type(8))) short;
using f32x4  = __attribute__((ext_vector_type(4))) float;
using s16x4  = __attribute__((ext_vector_type(4))) short;

__device__ inline short f2h(float x) {
  _Float16 h = (_Float16)x;  // RNE
  return __builtin_bit_cast(short, h);
}

__device__ inline unsigned pk2(float a, float b) {  // 2 fp32 -> packed 2xfp16
  h16x2 p = __builtin_amdgcn_cvt_pkrtz(a, b);
  return __builtin_bit_cast(unsigned, p);
}

__device__ inline f16x8 ld_frag_g(const short* p) {  // 16B aligned
  return __builtin_bit_cast(f16x8, *(const s16x8*)p);
}

#define GLOAD_LDS16(gsrc, ldst)                                              \
  __builtin_amdgcn_global_load_lds(                                          \
      (const __attribute__((address_space(1))) unsigned int*)(gsrc),         \
      (__attribute__((address_space(3))) unsigned int*)(ldst), 16, 0, 0)

// -------------------------------------------------------------------- prep
// blocks 0..6143  : xcvt  (slice = bid>>11, 4096 floats per block)
// blocks 6144..6911: wt_prep (Wt[slice][n][k] = W[k][n], 64x64 tiles)
__global__ __launch_bounds__(256) void prep(
    const float* __restrict__ Qx, const float* __restrict__ Kx,
    const float* __restrict__ Vx, const float* __restrict__ WQ,
    const float* __restrict__ WK, const float* __restrict__ WV,
    short* __restrict__ dq, short* __restrict__ dk, short* __restrict__ dv,
    short* __restrict__ wt) {
  __shared__ float t[64][65];
  const int bid = blockIdx.x;
  const int tid = threadIdx.x;
  if (bid < 6144) {
    const int slice = bid >> 11;
    const float* src = (slice == 0) ? Qx : (slice == 1) ? Kx : Vx;
    short* dst = (slice == 0) ? dq : (slice == 1) ? dk : dv;
    const size_t base = (size_t)(bid & 2047) * 4096;
#pragma unroll
    for (int j = 0; j < 4; ++j) {
      const size_t off = base + (size_t)(j * 256 + tid) * 4;
      float4 v = *(const float4*)(src + off);
      uint2 u = {pk2(v.x, v.y), pk2(v.z, v.w)};
      *(uint2*)(dst + off) = u;
    }
  } else {
    const int wid = bid - 6144;
    const int slice = wid >> 8;
    const int rem = wid & 255;
    const int n0 = (rem & 15) * 64, k0 = (rem >> 4) * 64;
    const float* W = (slice == 0) ? WQ : (slice == 1) ? WK : WV;
    {
      const int r = tid >> 2, c4 = tid & 3;
#pragma unroll
      for (int j = 0; j < 4; ++j) {
        float4 v = *(const float4*)(W + (size_t)(k0 + r) * D_ + n0 + c4 * 16 +
                                    j * 4);
        t[r][c4 * 16 + j * 4 + 0] = v.x;
        t[r][c4 * 16 + j * 4 + 1] = v.y;
        t[r][c4 * 16 + j * 4 + 2] = v.z;
        t[r][c4 * 16 + j * 4 + 3] = v.w;
      }
    }
    __syncthreads();
    {
      const int rn = tid >> 2, ks = tid & 3;
      short* dst =
          wt + ((size_t)slice << 20) + (size_t)(n0 + rn) * D_ + k0 + ks * 16;
      s16x4 h[4];
#pragma unroll
      for (int g = 0; g < 4; ++g)
#pragma unroll
        for (int j = 0; j < 4; ++j) h[g][j] = f2h(t[ks * 16 + g * 4 + j][rn]);
      *(s16x4*)(dst + 0) = h[0];
      *(s16x4*)(dst + 4) = h[1];
      *(s16x4*)(dst + 8) = h[2];
      *(s16x4*)(dst + 12) = h[3];
    }
  }
}

// ---------------------------------------------------------------- projections
// 768 blocks (3 slices x 256), 256 threads. Block tile 128(m) x 256(n), BK=32.
// 4 waves, each computes 128x64 (8x4 frags, 32 MFMA/step).
// Staging per thread per step: 2 A-gloads + 4 B-gloads (uniform 6) into
// rotating buffer (kt+2)%3; per step: s_waitcnt vmcnt(6) (oldest 6 = buf[kt]
// landed; 6 stay in flight across the barrier) -> s_barrier -> stage(kt+2) ->
// ds_read(swz) + 32 MFMA. XOR-granule swizzle keeps ds_read_b128 conflict-free.
__global__ __launch_bounds__(256, 2) void proj(
    const short* __restrict__ xq, const short* __restrict__ xk,
    const short* __restrict__ xv, const short* __restrict__ wt,
    short* __restrict__ qp, short* __restrict__ kp, short* __restrict__ vp) {
  __shared__ __align__(16) short As[3][128][32];
  __shared__ __align__(16) short Bs[3][256][32];
  const int gid = blockIdx.x;
  const int slice = gid >> 8, r = gid & 255;
  const short* A;
  const short* Bp;
  int m0, n0;
  float oscale;
  if (slice < 2) {
    A = slice ? xk : xq;              // rows = tokens (8192), 64 m-tiles
    Bp = wt + ((size_t)slice << 20);  // rows = H*Dh (1024), 4 n-tiles
    m0 = (r & 63) * 128;              // m-fast: 64 blocks share one Wt slab
    n0 = (r >> 6) * 256;
    oscale = slice ? 1.0f : 0.125f;
  } else {
    A = wt + ((size_t)2 << 20);  // rows = H*Dh (1024), 8 m-tiles
    Bp = xv;                     // rows = tokens (8192), 32 n-tiles
    m0 = (r & 7) * 128;          // m-fast: 8 blocks share one X token band
    n0 = (r >> 3) * 256;
    oscale = 1.0f;
  }

  const int tid = threadIdx.x;
  const int lane = tid & 63, w = tid >> 6;
  const int lr = lane & 15, lg = lane >> 4;
  const int g_row = tid >> 2, g_c = tid & 3;
  const int gsw = (g_c ^ ((g_row >> 1) & 3)) * 8;  // swizzled src granule
  const int rsw = (lg ^ ((lr >> 1) & 3)) * 8;      // swizzled read granule

  const short* ga = A + (size_t)(m0 + g_row) * D_ + gsw;
  const short* gb = Bp + (size_t)(n0 + g_row) * D_ + gsw;

  f32x4 acc[8][4];
#pragma unroll
  for (int i = 0; i < 8; ++i)
#pragma unroll
    for (int j = 0; j < 4; ++j) acc[i][j] = f32x4{0.f, 0.f, 0.f, 0.f};

#define STAGE(buf, kk)                                                        \
  do {                                                                        \
    GLOAD_LDS16(ga + (kk), &As[buf][g_row][g_c * 8]);                         \
    GLOAD_LDS16(ga + (size_t)64 * D_ + (kk), &As[buf][g_row + 64][g_c * 8]);  \
    GLOAD_LDS16(gb + (kk), &Bs[buf][g_row][g_c * 8]);                         \
    GLOAD_LDS16(gb + (size_t)64 * D_ + (kk), &Bs[buf][g_row + 64][g_c * 8]);  \
    GLOAD_LDS16(gb + (size_t)128 * D_ + (kk), &Bs[buf][g_row + 128][g_c * 8]);\
    GLOAD_LDS16(gb + (size_t)192 * D_ + (kk), &Bs[buf][g_row + 192][g_c * 8]);\
  } while (0)

  // prologue: stage buf0 (kt=0) and buf1 (kt=1); 12 loads outstanding
  STAGE(0, 0);
  STAGE(1, 32);

  for (int kt = 0; kt < 32; ++kt) {
    const int cur = kt % 3;
    if (kt < 31)
      asm volatile("s_waitcnt vmcnt(6)" ::: "memory");
    else
      asm volatile("s_waitcnt vmcnt(0)" ::: "memory");
    __builtin_amdgcn_s_barrier();
    __builtin_amdgcn_sched_barrier(0);
    if (kt < 30) {
      STAGE((kt + 2) % 3, (kt + 2) * 32);
    }

    f16x8 af[8], bf[4];
#pragma unroll
    for (int mi = 0; mi < 8; ++mi)
      af[mi] = ld_frag_g(&As[cur][mi * 16 + lr][rsw]);
#pragma unroll
    for (int ni = 0; ni < 4; ++ni)
      bf[ni] = ld_frag_g(&Bs[cur][w * 64 + ni * 16 + lr][rsw]);
#pragma unroll
    for (int mi = 0; mi < 8; ++mi)
#pragma unroll
      for (int ni = 0; ni < 4; ++ni)
        acc[mi][ni] = __builtin_amdgcn_mfma_f32_16x16x32_f16(
            af[mi], bf[ni], acc[mi][ni], 0, 0, 0);
  }
#undef STAGE

  // epilogue
  short* outp = (slice == 0) ? qp : kp;
#pragma unroll
  for (int mi = 0; mi < 8; ++mi)
#pragma unroll
    for (int ni = 0; ni < 4; ++ni) {
      const int mg0 = m0 + mi * 16 + lg * 4;
      const int ng = n0 + w * 64 + ni * 16 + lr;
#pragma unroll
      for (int reg = 0; reg < 4; ++reg) {
        const int m = mg0 + reg;
        const short val = f2h(acc[mi][ni][reg] * oscale);
        if (slice < 2) {
          const int b = m >> 10, s = m & 1023, hh = ng >> 6, dh = ng & 63;
          outp[((size_t)((b * H_ + hh) * S_) + s) * DH_ + dh] = val;
        } else {
          vp[((size_t)(ng >> 10) << 20) + (size_t)m * S_ + (ng & 1023)] = val;
        }
      }
    }
}

// ----------------------------------------------------------------- attention
// Block = (b, h, z): q-tiles {qtH=15-z, qtL=z}, ONE fused sweep over KV tiles;
// shared K/V tiles loaded once feed both halves' QK^T and PV MFMAs.
// Shift-free softmax (p = exp(s); exp(s - 1e12) == 0.0f exactly). Tiles with
// kv0 >= vlen skipped (vlen>0); vlen==0 degrades to plain causal softmax.
__global__ __launch_bounds__(256, 2) void attn_fwd(
    const short* __restrict__ qp, const short* __restrict__ kp,
    const short* __restrict__ vT, const int* __restrict__ Qlen,
    const int* __restrict__ Vlen, float* __restrict__ out) {
  __shared__ short Plds[2][4][16][72];
  const int bid = blockIdx.x;
  const int z = bid & 7;
  const int bh = bid >> 3;
  const int h = bh & 15;
  const int b = bh >> 4;
  const int lane = threadIdx.x & 63;
  const int w = threadIdx.x >> 6;
  const int lr = lane & 15, lg = lane >> 4;
  const short* qb = qp + (size_t)((b * H_ + h) * S_) * DH_;
  const short* kb = kp + (size_t)((b * H_ + h) * S_) * DH_;
  const short* vb = vT + (size_t)((b * H_ + h) * DH_) * S_;
  const int vlen = Vlen[b], qlen = Qlen[b];

  const int qtH = 15 - z, qtL = z;
  const int vcap = (vlen + 63) >> 6;
  const int nTH = (vlen > 0) ? min(qtH + 1, vcap) : (qtH + 1);
  const int nTL = (vlen > 0) ? min(qtL + 1, vcap) : (qtL + 1);
  const int q0H = qtH * 64 + w * 16;
  const int q0L = qtL * 64 + w * 16;

  f16x8 qfH[2], qfL[2];
#pragma unroll
  for (int c = 0; c < 2; ++c) {
    qfH[c] = ld_frag_g(qb + (size_t)(q0H + lr) * DH_ + c * 32 + lg * 8);
    qfL[c] = ld_frag_g(qb + (size_t)(q0L + lr) * DH_ + c * 32 + lg * 8);
  }

  float lH[4], lL[4];
  f32x4 oH[4], oL[4];
#pragma unroll
  for (int rr = 0; rr < 4; ++rr) {
    lH[rr] = 0.f; lL[rr] = 0.f;
    oH[rr] = f32x4{0.f, 0.f, 0.f, 0.f};
    oL[rr] = f32x4{0.f, 0.f, 0.f, 0.f};
  }

  f16x8 kf[8];
#pragma unroll
  for (int nt = 0; nt < 4; ++nt)
#pragma unroll
    for (int c = 0; c < 2; ++c)
      kf[nt * 2 + c] =
          ld_frag_g(kb + (size_t)(nt * 16 + lr) * DH_ + c * 32 + lg * 8);

  for (int t = 0; t < nTH; ++t) {
    const int kv0 = t * 64;
    const int kvn = (t + 1 < nTH) ? kv0 + 64 : kv0;
    const bool lact = t < nTL;

    f16x8 vf[8];
#pragma unroll
    for (int dt = 0; dt < 4; ++dt)
#pragma unroll
      for (int c = 0; c < 2; ++c)
        vf[dt * 2 + c] =
            ld_frag_g(vb + (size_t)(dt * 16 + lr) * S_ + kv0 + c * 32 + lg * 8);

    f16x8 kn[8];
#pragma unroll
    for (int nt = 0; nt < 4; ++nt)
#pragma unroll
      for (int c = 0; c < 2; ++c)
        kn[nt * 2 + c] = ld_frag_g(kb + (size_t)(kvn + nt * 16 + lr) * DH_ +
                                   c * 32 + lg * 8);

    f32x4 sH[4], sL[4];
#pragma unroll
    for (int nt = 0; nt < 4; ++nt) sH[nt] = f32x4{0.f, 0.f, 0.f, 0.f};
#pragma unroll
    for (int nt = 0; nt < 4; ++nt)
#pragma unroll
      for (int c = 0; c < 2; ++c)
        sH[nt] = __builtin_amdgcn_mfma_f32_16x16x32_f16(qfH[c], kf[nt * 2 + c],
                                                        sH[nt], 0, 0, 0);
    if (lact) {
#pragma unroll
      for (int nt = 0; nt < 4; ++nt) sL[nt] = f32x4{0.f, 0.f, 0.f, 0.f};
#pragma unroll
      for (int nt = 0; nt < 4; ++nt)
#pragma unroll
        for (int c = 0; c < 2; ++c)
          sL[nt] = __builtin_amdgcn_mfma_f32_16x16x32_f16(
              qfL[c], kf[nt * 2 + c], sL[nt], 0, 0, 0);
    }

    const bool km = (vlen > 0) && (vlen - kv0 < 64);

    if ((t == qtH) | km) {
#pragma unroll
      for (int reg = 0; reg < 4; ++reg) {
        const int qrow = q0H + lg * 4 + reg;
#pragma unroll
        for (int nt = 0; nt < 4; ++nt) {
          const int kv = kv0 + nt * 16 + lr;
          float sv = sH[nt][reg];
          if (km && kv >= vlen) sv -= 1e12f;
          if (kv > qrow) sv -= 1e12f;
          const float p = __expf(sv);
          lH[reg] += p;
          Plds[0][w][lg * 4 + reg][nt * 16 + lr] = f2h(p);
        }
      }
    } else {
#pragma unroll
      for (int reg = 0; reg < 4; ++reg)
#pragma unroll
        for (int nt = 0; nt < 4; ++nt) {
          const float p = __expf(sH[nt][reg]);
          lH[reg] += p;
          Plds[0][w][lg * 4 + reg][nt * 16 + lr] = f2h(p);
        }
    }
    if (lact) {
      if ((t == qtL) | km) {
#pragma unroll
        for (int reg = 0; reg < 4; ++reg) {
          const int qrow = q0L + lg * 4 + reg;
#pragma unroll
          for (int nt = 0; nt < 4; ++nt) {
            const int kv = kv0 + nt * 16 + lr;
            float sv = sL[nt][reg];
            if (km && kv >= vlen) sv -= 1e12f;
            if (kv > qrow) sv -= 1e12f;
            const float p = __expf(sv);
            lL[reg] += p;
            Plds[1][w][lg * 4 + reg][nt * 16 + lr] = f2h(p);
          }
        }
      } else {
#pragma unroll
        for (int reg = 0; reg < 4; ++reg)
#pragma unroll
          for (int nt = 0; nt < 4; ++nt) {
            const float p = __expf(sL[nt][reg]);
            lL[reg] += p;
            Plds[1][w][lg * 4 + reg][nt * 16 + lr] = f2h(p);
          }
      }
    }

#pragma unroll
    for (int c = 0; c < 2; ++c) {
      s16x4 a0 = *(const s16x4*)(&Plds[0][w][lr][c * 32 + lg * 8]);
      s16x4 a1 = *(const s16x4*)(&Plds[0][w][lr][c * 32 + lg * 8 + 4]);
      s16x8 pr = {a0[0], a0[1], a0[2], a0[3], a1[0], a1[1], a1[2], a1[3]};
      f16x8 paH = __builtin_bit_cast(f16x8, pr);
#pragma unroll
      for (int dt = 0; dt < 4; ++dt)
        oH[dt] = __builtin_amdgcn_mfma_f32_16x16x32_f16(paH, vf[dt * 2 + c],
                                                        oH[dt], 0, 0, 0);
    }
    if (lact) {
#pragma unroll
      for (int c = 0; c < 2; ++c) {
        s16x4 a0 = *(const s16x4*)(&Plds[1][w][lr][c * 32 + lg * 8]);
        s16x4 a1 = *(const s16x4*)(&Plds[1][w][lr][c * 32 + lg * 8 + 4]);
        s16x8 pr = {a0[0], a0[1], a0[2], a0[3], a1[0], a1[1], a1[2], a1[3]};
        f16x8 paL = __builtin_bit_cast(f16x8, pr);
#pragma unroll
        for (int dt = 0; dt < 4; ++dt)
          oL[dt] = __builtin_amdgcn_mfma_f32_16x16x32_f16(paL, vf[dt * 2 + c],
                                                          oL[dt], 0, 0, 0);
      }
    }

#pragma unroll
    for (int i = 0; i < 8; ++i) kf[i] = kn[i];
  }

#pragma unroll
  for (int reg = 0; reg < 4; ++reg) {
    float ls = lH[reg];
    ls += __shfl_xor(ls, 1);
    ls += __shfl_xor(ls, 2);
    ls += __shfl_xor(ls, 4);
    ls += __shfl_xor(ls, 8);
    const int qrow = q0H + lg * 4 + reg;
    const float sc = (qrow < qlen) ? (1.f / ls) : 0.f;
#pragma unroll
    for (int dt = 0; dt < 4; ++dt)
      out[(size_t)(b * S_ + qrow) * D_ + h * DH_ + dt * 16 + lr] =
          oH[dt][reg] * sc;
  }
#pragma unroll
  for (int reg = 0; reg < 4; ++reg) {
    float ls = lL[reg];
    ls += __shfl_xor(ls, 1);
    ls += __shfl_xor(ls, 2);
    ls += __shfl_xor(ls, 4);
    ls += __shfl_xor(ls, 8);
    const int qrow = q0L + lg * 4 + reg;
    const float sc = (qrow < qlen) ? (1.f / ls) : 0.f;
#pragma unroll
    for (int dt = 0; dt < 4; ++dt)
      out[(size_t)(b * S_ + qrow) * D_ + h * DH_ + dt * 16 + lr] =
          oL[dt][reg] * sc;
  }
}

// ------------------------------------------------------------------- launch
extern "C" void kernel_launch(void* const* d_in, const int* in_sizes, int n_in,
                              void* d_out, int out_size, void* d_ws,
                              size_t ws_size, hipStream_t stream) {
  const float* Q = (const float*)d_in[0];
  const float* K = (const float*)d_in[1];
  const float* V = (const float*)d_in[2];
  const float* WQ = (const float*)d_in[3];
  const float* WK = (const float*)d_in[4];
  const float* WV = (const float*)d_in[5];
  const int* Qlen = (const int*)d_in[6];
  const int* Vlen = (const int*)d_in[7];
  float* out = (float*)d_out;

  const size_t PE = (size_t)B_ * H_ * S_ * DH_;  // 8388608 elements
  short* qp = (short*)d_ws;
  short* kp = qp + PE;
  short* vT = kp + PE;
  short* wt = vT + PE;            // 3 x 1M fp16 = 6MB
  short* xhV = wt + 3 * 1048576;  // 16MB (ws total 70MB)
  // Q/K fp16 scratch lives in d_out (33.5MB >= 32MB); attn_fwd fully
  // overwrites d_out afterwards, so this is deterministic & safe.
  short* xhQ = (short*)d_out;
  short* xhK = xhQ + PE;

  prep<<<dim3(6912), dim3(256), 0, stream>>>(Q, K, V, WQ, WK, WV, xhQ, xhK,
                                             xhV, wt);
  proj<<<dim3(768), dim3(256), 0, stream>>>(xhQ, xhK, xhV, wt, qp, kp, vT);
  attn_fwd<<<dim3(1024), dim3(256), 0, stream>>>(qp, kp, vT, Qlen, Vlen, out);
}

// Round 12
// 163.322 us; speedup vs baseline: 1.0718x; 1.0718x over previous
//
#include <hip/hip_runtime.h>
#include <hip/hip_bf16.h>

// SelfAttention: O = softmax(mask((X_q WQ)(X_k WK)^T/8)) (X_v WV), causal +
// key-padding (V_len) + query (Q_len) masks. B=8 S=1024 D=1024 H=16 Dh=64.
//
// All intermediates FP16. Pipeline:
//   prep    : X fp32->fp16 (8192 floats/block, 16B packed stores) + Wt
//             transpose, one dispatch (3840 blocks).
//   proj    : ONE dispatch, 1536 blocks; 128^2 tile, BK=32; both operands via
//             global_load_lds w16 into THREE rotating LDS buffers; counted
//             s_waitcnt vmcnt(4) + raw s_barrier per step; XOR-granule
//             swizzle on source+read (conflict-free ds_read_b128).
//   attn_fwd: flash attention, shift-free softmax, vlen tile skipping, fused
//             q-tile pairs {15-z, z} per block (K/V tiles loaded once).

#define B_  8
#define S_  1024
#define D_  1024
#define H_  16
#define DH_ 64

using f16x8  = __attribute__((ext_vector_type(8))) _Float16;
using h16x2  = __attribute__((ext_vector_type(2))) __fp16;  // cvt_pkrtz result
using s16x8  = __attribute__((ext_vector_type(8))) short;
using f32x4  = __attribute__((ext_vector_type(4))) float;
using s16x4  = __attribute__((ext_vector_type(4))) short;

__device__ inline short f2h(float x) {
  _Float16 h = (_Float16)x;  // RNE
  return __builtin_bit_cast(short, h);
}

__device__ inline unsigned pk2(float a, float b) {  // 2 fp32 -> packed 2xfp16
  h16x2 p = __builtin_amdgcn_cvt_pkrtz(a, b);
  return __builtin_bit_cast(unsigned, p);
}

__device__ inline f16x8 ld_frag_g(const short* p) {  // 16B aligned
  return __builtin_bit_cast(f16x8, *(const s16x8*)p);
}

#define GLOAD_LDS16(gsrc, ldst)                                              \
  __builtin_amdgcn_global_load_lds(                                          \
      (const __attribute__((address_space(1))) unsigned int*)(gsrc),         \
      (__attribute__((address_space(3))) unsigned int*)(ldst), 16, 0, 0)

// -------------------------------------------------------------------- prep
// blocks 0..3071  : xcvt (slice = bid>>10, 8192 floats per block; per thread
//                   4 x {2 float4 loads -> 1 uint4 (16B) store})
// blocks 3072..3839: wt_prep (Wt[slice][n][k] = W[k][n], 64x64 tiles)
__global__ __launch_bounds__(256) void prep(
    const float* __restrict__ Qx, const float* __restrict__ Kx,
    const float* __restrict__ Vx, const float* __restrict__ WQ,
    const float* __restrict__ WK, const float* __restrict__ WV,
    short* __restrict__ dq, short* __restrict__ dk, short* __restrict__ dv,
    short* __restrict__ wt) {
  __shared__ float t[64][65];
  const int bid = blockIdx.x;
  const int tid = threadIdx.x;
  if (bid < 3072) {
    const int slice = bid >> 10;
    const float* src = (slice == 0) ? Qx : (slice == 1) ? Kx : Vx;
    short* dst = (slice == 0) ? dq : (slice == 1) ? dk : dv;
    const size_t base = (size_t)(bid & 1023) * 8192;
#pragma unroll
    for (int j = 0; j < 4; ++j) {
      const size_t off = base + (size_t)j * 2048 + (size_t)tid * 8;
      float4 a = *(const float4*)(src + off);
      float4 b = *(const float4*)(src + off + 4);
      uint4 u = {pk2(a.x, a.y), pk2(a.z, a.w), pk2(b.x, b.y), pk2(b.z, b.w)};
      *(uint4*)(dst + off) = u;
    }
  } else {
    const int wid = bid - 3072;
    const int slice = wid >> 8;
    const int rem = wid & 255;
    const int n0 = (rem & 15) * 64, k0 = (rem >> 4) * 64;
    const float* W = (slice == 0) ? WQ : (slice == 1) ? WK : WV;
    {
      const int r = tid >> 2, c4 = tid & 3;
#pragma unroll
      for (int j = 0; j < 4; ++j) {
        float4 v = *(const float4*)(W + (size_t)(k0 + r) * D_ + n0 + c4 * 16 +
                                    j * 4);
        t[r][c4 * 16 + j * 4 + 0] = v.x;
        t[r][c4 * 16 + j * 4 + 1] = v.y;
        t[r][c4 * 16 + j * 4 + 2] = v.z;
        t[r][c4 * 16 + j * 4 + 3] = v.w;
      }
    }
    __syncthreads();
    {
      const int rn = tid >> 2, ks = tid & 3;
      short* dst =
          wt + ((size_t)slice << 20) + (size_t)(n0 + rn) * D_ + k0 + ks * 16;
      s16x4 h[4];
#pragma unroll
      for (int g = 0; g < 4; ++g)
#pragma unroll
        for (int j = 0; j < 4; ++j) h[g][j] = f2h(t[ks * 16 + g * 4 + j][rn]);
      *(s16x4*)(dst + 0) = h[0];
      *(s16x4*)(dst + 4) = h[1];
      *(s16x4*)(dst + 8) = h[2];
      *(s16x4*)(dst + 12) = h[3];
    }
  }
}

// ---------------------------------------------------------------- projections
// 1536 blocks (3 slices x 512), 256 threads, 128x128 tile, BK=32.
// THREE rotating [128][32] buffers per operand; stage depth 2; per step:
//   s_waitcnt vmcnt(4); s_barrier; stage buf[t+2]; ds_read(swz) + 16 MFMA.
// XOR-granule swizzle (src+read involution) keeps ds_read_b128 conflict-free.
__global__ __launch_bounds__(256, 3) void proj(
    const short* __restrict__ xq, const short* __restrict__ xk,
    const short* __restrict__ xv, const short* __restrict__ wt,
    short* __restrict__ qp, short* __restrict__ kp, short* __restrict__ vp) {
  __shared__ __align__(16) short As[3][128][32];
  __shared__ __align__(16) short Bs[3][128][32];
  const int gid = blockIdx.x;
  const int slice = gid >> 9, r = gid & 511;
  const short* A;
  const short* Bp;
  int m0, n0;
  float oscale;
  if (slice < 2) {
    A = slice ? xk : xq;              // rows = tokens (8192)
    Bp = wt + ((size_t)slice << 20);  // rows = H*Dh (1024)
    m0 = (r & 63) * 128;              // m-fast: 64 blocks share one Wt slab
    n0 = (r >> 6) * 128;
    oscale = slice ? 1.0f : 0.125f;
  } else {
    A = wt + ((size_t)2 << 20);  // rows = H*Dh
    Bp = xv;                     // rows = tokens (8192)
    m0 = (r & 7) * 128;          // m-fast: 8 blocks share one X token band
    n0 = (r >> 3) * 128;
    oscale = 1.0f;
  }

  const int tid = threadIdx.x;
  const int lane = tid & 63, w = tid >> 6;
  const int wr = w >> 1, wc = w & 1;
  const int lr = lane & 15, lg = lane >> 4;
  const int g_row = tid >> 2, g_c = tid & 3;
  const int gsw = (g_c ^ ((g_row >> 1) & 3)) * 8;  // swizzled src granule
  const int rsw = (lg ^ ((lr >> 1) & 3)) * 8;      // swizzled read granule

  const short* ga = A + (size_t)(m0 + g_row) * D_ + gsw;
  const short* gb = Bp + (size_t)(n0 + g_row) * D_ + gsw;

  f32x4 acc[4][4];
#pragma unroll
  for (int i = 0; i < 4; ++i)
#pragma unroll
    for (int j = 0; j < 4; ++j) acc[i][j] = f32x4{0.f, 0.f, 0.f, 0.f};

  // prologue: stage buf0 (kt=0) and buf1 (kt=1); 8 loads outstanding
  GLOAD_LDS16(ga, &As[0][g_row][g_c * 8]);
  GLOAD_LDS16(ga + (size_t)64 * D_, &As[0][g_row + 64][g_c * 8]);
  GLOAD_LDS16(gb, &Bs[0][g_row][g_c * 8]);
  GLOAD_LDS16(gb + (size_t)64 * D_, &Bs[0][g_row + 64][g_c * 8]);
  GLOAD_LDS16(ga + 32, &As[1][g_row][g_c * 8]);
  GLOAD_LDS16(ga + (size_t)64 * D_ + 32, &As[1][g_row + 64][g_c * 8]);
  GLOAD_LDS16(gb + 32, &Bs[1][g_row][g_c * 8]);
  GLOAD_LDS16(gb + (size_t)64 * D_ + 32, &Bs[1][g_row + 64][g_c * 8]);

  for (int kt = 0; kt < 32; ++kt) {
    const int cur = kt % 3;
    if (kt < 30)
      asm volatile("s_waitcnt vmcnt(4)" ::: "memory");
    else
      asm volatile("s_waitcnt vmcnt(0)" ::: "memory");
    __builtin_amdgcn_s_barrier();
    __builtin_amdgcn_sched_barrier(0);
    if (kt < 30) {
      const int pre = (kt + 2) % 3;
      const int k2 = (kt + 2) * 32;
      GLOAD_LDS16(ga + k2, &As[pre][g_row][g_c * 8]);
      GLOAD_LDS16(ga + (size_t)64 * D_ + k2, &As[pre][g_row + 64][g_c * 8]);
      GLOAD_LDS16(gb + k2, &Bs[pre][g_row][g_c * 8]);
      GLOAD_LDS16(gb + (size_t)64 * D_ + k2, &Bs[pre][g_row + 64][g_c * 8]);
    }

    f16x8 af[4], bf[4];
#pragma unroll
    for (int mi = 0; mi < 4; ++mi)
      af[mi] = ld_frag_g(&As[cur][wr * 64 + mi * 16 + lr][rsw]);
#pragma unroll
    for (int ni = 0; ni < 4; ++ni)
      bf[ni] = ld_frag_g(&Bs[cur][wc * 64 + ni * 16 + lr][rsw]);
#pragma unroll
    for (int mi = 0; mi < 4; ++mi)
#pragma unroll
      for (int ni = 0; ni < 4; ++ni)
        acc[mi][ni] = __builtin_amdgcn_mfma_f32_16x16x32_f16(
            af[mi], bf[ni], acc[mi][ni], 0, 0, 0);
  }

  // epilogue
  short* outp = (slice == 0) ? qp : kp;
#pragma unroll
  for (int mi = 0; mi < 4; ++mi)
#pragma unroll
    for (int ni = 0; ni < 4; ++ni) {
      const int mg0 = m0 + wr * 64 + mi * 16 + lg * 4;
      const int ng = n0 + wc * 64 + ni * 16 + lr;
#pragma unroll
      for (int reg = 0; reg < 4; ++reg) {
        const int m = mg0 + reg;
        const short val = f2h(acc[mi][ni][reg] * oscale);
        if (slice < 2) {
          const int b = m >> 10, s = m & 1023, hh = ng >> 6, dh = ng & 63;
          outp[((size_t)((b * H_ + hh) * S_) + s) * DH_ + dh] = val;
        } else {
          vp[((size_t)(ng >> 10) << 20) + (size_t)m * S_ + (ng & 1023)] = val;
        }
      }
    }
}

// ----------------------------------------------------------------- attention
// Block = (b, h, z): q-tiles {qtH=15-z, qtL=z}, ONE fused sweep over KV tiles;
// shared K/V tiles loaded once feed both halves' QK^T and PV MFMAs.
// Shift-free softmax (p = exp(s); exp(s - 1e12) == 0.0f exactly). Tiles with
// kv0 >= vlen skipped (vlen>0); vlen==0 degrades to plain causal softmax.
__global__ __launch_bounds__(256, 2) void attn_fwd(
    const short* __restrict__ qp, const short* __restrict__ kp,
    const short* __restrict__ vT, const int* __restrict__ Qlen,
    const int* __restrict__ Vlen, float* __restrict__ out) {
  __shared__ short Plds[2][4][16][72];
  const int bid = blockIdx.x;
  const int z = bid & 7;
  const int bh = bid >> 3;
  const int h = bh & 15;
  const int b = bh >> 4;
  const int lane = threadIdx.x & 63;
  const int w = threadIdx.x >> 6;
  const int lr = lane & 15, lg = lane >> 4;
  const short* qb = qp + (size_t)((b * H_ + h) * S_) * DH_;
  const short* kb = kp + (size_t)((b * H_ + h) * S_) * DH_;
  const short* vb = vT + (size_t)((b * H_ + h) * DH_) * S_;
  const int vlen = Vlen[b], qlen = Qlen[b];

  const int qtH = 15 - z, qtL = z;
  const int vcap = (vlen + 63) >> 6;
  const int nTH = (vlen > 0) ? min(qtH + 1, vcap) : (qtH + 1);
  const int nTL = (vlen > 0) ? min(qtL + 1, vcap) : (qtL + 1);
  const int q0H = qtH * 64 + w * 16;
  const int q0L = qtL * 64 + w * 16;

  f16x8 qfH[2], qfL[2];
#pragma unroll
  for (int c = 0; c < 2; ++c) {
    qfH[c] = ld_frag_g(qb + (size_t)(q0H + lr) * DH_ + c * 32 + lg * 8);
    qfL[c] = ld_frag_g(qb + (size_t)(q0L + lr) * DH_ + c * 32 + lg * 8);
  }

  float lH[4], lL[4];
  f32x4 oH[4], oL[4];
#pragma unroll
  for (int rr = 0; rr < 4; ++rr) {
    lH[rr] = 0.f; lL[rr] = 0.f;
    oH[rr] = f32x4{0.f, 0.f, 0.f, 0.f};
    oL[rr] = f32x4{0.f, 0.f, 0.f, 0.f};
  }

  f16x8 kf[8];
#pragma unroll
  for (int nt = 0; nt < 4; ++nt)
#pragma unroll
    for (int c = 0; c < 2; ++c)
      kf[nt * 2 + c] =
          ld_frag_g(kb + (size_t)(nt * 16 + lr) * DH_ + c * 32 + lg * 8);

  for (int t = 0; t < nTH; ++t) {
    const int kv0 = t * 64;
    const int kvn = (t + 1 < nTH) ? kv0 + 64 : kv0;
    const bool lact = t < nTL;

    f16x8 vf[8];
#pragma unroll
    for (int dt = 0; dt < 4; ++dt)
#pragma unroll
      for (int c = 0; c < 2; ++c)
        vf[dt * 2 + c] =
            ld_frag_g(vb + (size_t)(dt * 16 + lr) * S_ + kv0 + c * 32 + lg * 8);

    f16x8 kn[8];
#pragma unroll
    for (int nt = 0; nt < 4; ++nt)
#pragma unroll
      for (int c = 0; c < 2; ++c)
        kn[nt * 2 + c] = ld_frag_g(kb + (size_t)(kvn + nt * 16 + lr) * DH_ +
                                   c * 32 + lg * 8);

    f32x4 sH[4], sL[4];
#pragma unroll
    for (int nt = 0; nt < 4; ++nt) sH[nt] = f32x4{0.f, 0.f, 0.f, 0.f};
#pragma unroll
    for (int nt = 0; nt < 4; ++nt)
#pragma unroll
      for (int c = 0; c < 2; ++c)
        sH[nt] = __builtin_amdgcn_mfma_f32_16x16x32_f16(qfH[c], kf[nt * 2 + c],
                                                        sH[nt], 0, 0, 0);
    if (lact) {
#pragma unroll
      for (int nt = 0; nt < 4; ++nt) sL[nt] = f32x4{0.f, 0.f, 0.f, 0.f};
#pragma unroll
      for (int nt = 0; nt < 4; ++nt)
#pragma unroll
        for (int c = 0; c < 2; ++c)
          sL[nt] = __builtin_amdgcn_mfma_f32_16x16x32_f16(
              qfL[c], kf[nt * 2 + c], sL[nt], 0, 0, 0);
    }

    const bool km = (vlen > 0) && (vlen - kv0 < 64);

    if ((t == qtH) | km) {
#pragma unroll
      for (int reg = 0; reg < 4; ++reg) {
        const int qrow = q0H + lg * 4 + reg;
#pragma unroll
        for (int nt = 0; nt < 4; ++nt) {
          const int kv = kv0 + nt * 16 + lr;
          float sv = sH[nt][reg];
          if (km && kv >= vlen) sv -= 1e12f;
          if (kv > qrow) sv -= 1e12f;
          const float p = __expf(sv);
          lH[reg] += p;
          Plds[0][w][lg * 4 + reg][nt * 16 + lr] = f2h(p);
        }
      }
    } else {
#pragma unroll
      for (int reg = 0; reg < 4; ++reg)
#pragma unroll
        for (int nt = 0; nt < 4; ++nt) {
          const float p = __expf(sH[nt][reg]);
          lH[reg] += p;
          Plds[0][w][lg * 4 + reg][nt * 16 + lr] = f2h(p);
        }
    }
    if (lact) {
      if ((t == qtL) | km) {
#pragma unroll
        for (int reg = 0; reg < 4; ++reg) {
          const int qrow = q0L + lg * 4 + reg;
#pragma unroll
          for (int nt = 0; nt < 4; ++nt) {
            const int kv = kv0 + nt * 16 + lr;
            float sv = sL[nt][reg];
            if (km && kv >= vlen) sv -= 1e12f;
            if (kv > qrow) sv -= 1e12f;
            const float p = __expf(sv);
            lL[reg] += p;
            Plds[1][w][lg * 4 + reg][nt * 16 + lr] = f2h(p);
          }
        }
      } else {
#pragma unroll
        for (int reg = 0; reg < 4; ++reg)
#pragma unroll
          for (int nt = 0; nt < 4; ++nt) {
            const float p = __expf(sL[nt][reg]);
            lL[reg] += p;
            Plds[1][w][lg * 4 + reg][nt * 16 + lr] = f2h(p);
          }
      }
    }

#pragma unroll
    for (int c = 0; c < 2; ++c) {
      s16x4 a0 = *(const s16x4*)(&Plds[0][w][lr][c * 32 + lg * 8]);
      s16x4 a1 = *(const s16x4*)(&Plds[0][w][lr][c * 32 + lg * 8 + 4]);
      s16x8 pr = {a0[0], a0[1], a0[2], a0[3], a1[0], a1[1], a1[2], a1[3]};
      f16x8 paH = __builtin_bit_cast(f16x8, pr);
#pragma unroll
      for (int dt = 0; dt < 4; ++dt)
        oH[dt] = __builtin_amdgcn_mfma_f32_16x16x32_f16(paH, vf[dt * 2 + c],
                                                        oH[dt], 0, 0, 0);
    }
    if (lact) {
#pragma unroll
      for (int c = 0; c < 2; ++c) {
        s16x4 a0 = *(const s16x4*)(&Plds[1][w][lr][c * 32 + lg * 8]);
        s16x4 a1 = *(const s16x4*)(&Plds[1][w][lr][c * 32 + lg * 8 + 4]);
        s16x8 pr = {a0[0], a0[1], a0[2], a0[3], a1[0], a1[1], a1[2], a1[3]};
        f16x8 paL = __builtin_bit_cast(f16x8, pr);
#pragma unroll
        for (int dt = 0; dt < 4; ++dt)
          oL[dt] = __builtin_amdgcn_mfma_f32_16x16x32_f16(paL, vf[dt * 2 + c],
                                                          oL[dt], 0, 0, 0);
      }
    }

#pragma unroll
    for (int i = 0; i < 8; ++i) kf[i] = kn[i];
  }

#pragma unroll
  for (int reg = 0; reg < 4; ++reg) {
    float ls = lH[reg];
    ls += __shfl_xor(ls, 1);
    ls += __shfl_xor(ls, 2);
    ls += __shfl_xor(ls, 4);
    ls += __shfl_xor(ls, 8);
    const int qrow = q0H + lg * 4 + reg;
    const float sc = (qrow < qlen) ? (1.f / ls) : 0.f;
#pragma unroll
    for (int dt = 0; dt < 4; ++dt)
      out[(size_t)(b * S_ + qrow) * D_ + h * DH_ + dt * 16 + lr] =
          oH[dt][reg] * sc;
  }
#pragma unroll
  for (int reg = 0; reg < 4; ++reg) {
    float ls = lL[reg];
    ls += __shfl_xor(ls, 1);
    ls += __shfl_xor(ls, 2);
    ls += __shfl_xor(ls, 4);
    ls += __shfl_xor(ls, 8);
    const int qrow = q0L + lg * 4 + reg;
    const float sc = (qrow < qlen) ? (1.f / ls) : 0.f;
#pragma unroll
    for (int dt = 0; dt < 4; ++dt)
      out[(size_t)(b * S_ + qrow) * D_ + h * DH_ + dt * 16 + lr] =
          oL[dt][reg] * sc;
  }
}

// ------------------------------------------------------------------- launch
extern "C" void kernel_launch(void* const* d_in, const int* in_sizes, int n_in,
                              void* d_out, int out_size, void* d_ws,
                              size_t ws_size, hipStream_t stream) {
  const float* Q = (const float*)d_in[0];
  const float* K = (const float*)d_in[1];
  const float* V = (const float*)d_in[2];
  const float* WQ = (const float*)d_in[3];
  const float* WK = (const float*)d_in[4];
  const float* WV = (const float*)d_in[5];
  const int* Qlen = (const int*)d_in[6];
  const int* Vlen = (const int*)d_in[7];
  float* out = (float*)d_out;

  const size_t PE = (size_t)B_ * H_ * S_ * DH_;  // 8388608 elements
  short* qp = (short*)d_ws;
  short* kp = qp + PE;
  short* vT = kp + PE;
  short* wt = vT + PE;            // 3 x 1M fp16 = 6MB
  short* xhV = wt + 3 * 1048576;  // 16MB (ws total 70MB)
  // Q/K fp16 scratch lives in d_out (33.5MB >= 32MB); attn_fwd fully
  // overwrites d_out afterwards, so this is deterministic & safe.
  short* xhQ = (short*)d_out;
  short* xhK = xhQ + PE;

  prep<<<dim3(3840), dim3(256), 0, stream>>>(Q, K, V, WQ, WK, WV, xhQ, xhK,
                                             xhV, wt);
  proj<<<dim3(1536), dim3(256), 0, stream>>>(xhQ, xhK, xhV, wt, qp, kp, vT);
  attn_fwd<<<dim3(1024), dim3(256), 0, stream>>>(qp, kp, vT, Qlen, Vlen, out);
}